// Round 4
// baseline (735.320 us; speedup 1.0000x reference)
//
#include <hip/hip_runtime.h>
#include <hip/hip_bf16.h>
#include <math.h>

#define BB 32
#define SS 4096
#define EE 512
#define AA 512

typedef short bf16x8 __attribute__((ext_vector_type(8)));
typedef float f32x4 __attribute__((ext_vector_type(4)));

__device__ __forceinline__ unsigned short f2bf(float f) {
  unsigned int u = __float_as_uint(f);
  u += 0x7fffu + ((u >> 16) & 1u);   // RNE (finite normals)
  return (unsigned short)(u >> 16);
}

__device__ __forceinline__ float tanh_fast(float x) {
  return 1.f - 2.f / (__expf(2.f * x) + 1.f);
}

// pack 8 f32 -> bf16x8 (RNE) via packed cvt
__device__ __forceinline__ bf16x8 pack8(float4 a, float4 b) {
  union { bf16x8 v; __hip_bfloat162 h[4]; } u;
  u.h[0] = __float22bfloat162_rn(make_float2(a.x, a.y));
  u.h[1] = __float22bfloat162_rn(make_float2(a.z, a.w));
  u.h[2] = __float22bfloat162_rn(make_float2(b.x, b.y));
  u.h[3] = __float22bfloat162_rn(make_float2(b.z, b.w));
  return u.v;
}

// q[b][a] = sum_e h[b][e] * Wh[e][a]
__global__ void query_kernel(const float* __restrict__ h,
                             const float* __restrict__ Wh,
                             float* __restrict__ q) {
  __shared__ float hrow[EE];
  int b = blockIdx.x;
  int t = threadIdx.x;
  for (int i = t; i < EE; i += 256) hrow[i] = h[b * EE + i];
  __syncthreads();
  float a0 = 0.f, a1 = 0.f;
  for (int e = 0; e < EE; ++e) {
    float hv = hrow[e];
    a0 += hv * Wh[e * AA + t];
    a1 += hv * Wh[e * AA + t + 256];
  }
  q[b * AA + t] = a0;
  q[b * AA + t + 256] = a1;
}

// Wst[a][e] = bf16(Ws[e][a])
__global__ void wst_kernel(const float* __restrict__ Ws,
                           unsigned short* __restrict__ Wst) {
  int i = blockIdx.x * 256 + threadIdx.x;   // over 512*512
  int a = i >> 9, e = i & 511;
  Wst[a * EE + e] = f2bf(Ws[e * AA + a]);
}

// Fused, LDS-free GEMM: block = (chunk of 64 s-rows, b). 4 waves, wave w owns
// n in [w*128, w*128+128) (2 passes of N=64), M=64, K=512. A-frags loaded
// straight from global enc (f32) and packed to bf16 in-register; B-frags from
// L2-resident Wst. No barrier until the score-reduce tail.
__global__ __launch_bounds__(256, 3) void fused_kernel(
    const float* __restrict__ enc, const unsigned short* __restrict__ Wst,
    const float* __restrict__ q, const float* __restrict__ v,
    const int* __restrict__ mask,
    float* __restrict__ rawscore,   // -> attn region of d_out
    float* __restrict__ ctxp,       // [32][64][512]
    float* __restrict__ mbuf) {     // [32][64]
  __shared__ float spart[4][64];
  __shared__ float wrow[64];
  const int b = blockIdx.y, chunk = blockIdx.x;
  const int s0 = chunk * 64;
  const int tid = threadIdx.x;
  const int w = tid >> 6, lane = tid & 63;
  const int quad = lane >> 4, l16 = lane & 15;

  const float* encB = enc + (size_t)b * SS * EE;
  const float* aPtr[4];
#pragma unroll
  for (int m = 0; m < 4; ++m)
    aPtr[m] = encB + (size_t)(s0 + m * 16 + l16) * EE + quad * 8;

  float srow[4][4];   // [m][r] partial row-scores over this wave's 128 cols
#pragma unroll
  for (int m = 0; m < 4; ++m)
#pragma unroll
    for (int r = 0; r < 4; ++r) srow[m][r] = 0.f;

  for (int h = 0; h < 2; ++h) {
    const int n0 = w * 128 + h * 64;
    f32x4 acc[4][4];   // [m][n]
#pragma unroll
    for (int m = 0; m < 4; ++m)
#pragma unroll
      for (int n = 0; n < 4; ++n) acc[m][n] = (f32x4){0.f, 0.f, 0.f, 0.f};

    const unsigned short* wb = Wst + (size_t)(n0 + l16) * EE + quad * 8;
#pragma unroll 4
    for (int k0 = 0; k0 < 512; k0 += 32) {
      bf16x8 aF[4], bF[4];
#pragma unroll
      for (int m = 0; m < 4; ++m) {
        float4 f0 = *(const float4*)(aPtr[m] + k0);
        float4 f1 = *(const float4*)(aPtr[m] + k0 + 4);
        aF[m] = pack8(f0, f1);
      }
#pragma unroll
      for (int n = 0; n < 4; ++n)
        bF[n] = *(const bf16x8*)&wb[(size_t)n * 16 * EE + k0];
#pragma unroll
      for (int m = 0; m < 4; ++m)
#pragma unroll
        for (int n = 0; n < 4; ++n)
          acc[m][n] = __builtin_amdgcn_mfma_f32_16x16x32_bf16(
              aF[m], bF[n], acc[m][n], 0, 0, 0);
    }
    // epilogue: tanh + v-weighted accumulate
#pragma unroll
    for (int n = 0; n < 4; ++n) {
      float qn = q[b * AA + n0 + n * 16 + l16];
      float vn = v[n0 + n * 16 + l16];
#pragma unroll
      for (int m = 0; m < 4; ++m)
#pragma unroll
        for (int r = 0; r < 4; ++r)
          srow[m][r] += tanh_fast(qn + acc[m][n][r]) * vn;
    }
  }

  // reduce across the 16 lanes (n-cols) of each quad
#pragma unroll
  for (int m = 0; m < 4; ++m)
#pragma unroll
    for (int r = 0; r < 4; ++r) {
      float s = srow[m][r];
      s += __shfl_xor(s, 1, 64);
      s += __shfl_xor(s, 2, 64);
      s += __shfl_xor(s, 4, 64);
      s += __shfl_xor(s, 8, 64);
      if (l16 == 0) spart[w][m * 16 + quad * 4 + r] = s;
    }
  __syncthreads();

  // Phase C: masked raw scores, chunk max, exp weights (wave 0 only)
  if (tid < 64) {
    float raw = spart[0][tid] + spart[1][tid] + spart[2][tid] + spart[3][tid];
    float sc = mask[(size_t)b * SS + s0 + tid] ? -1e9f : raw;
    rawscore[(size_t)b * SS + s0 + tid] = sc;
    float mx = sc;
    for (int off = 1; off < 64; off <<= 1)
      mx = fmaxf(mx, __shfl_xor(mx, off, 64));
    wrow[tid] = __expf(sc - mx);
    if (tid == 0) mbuf[b * 64 + chunk] = mx;
  }
  __syncthreads();

  // Phase D: ctx partial from global f32 enc (L2-hot); thread owns 2 e-cols
  {
    const int e0 = tid * 2;
    float ax = 0.f, ay = 0.f;
    const float* ep = encB + (size_t)s0 * EE + e0;
#pragma unroll 8
    for (int row = 0; row < 64; ++row) {
      float wgt = wrow[row];
      float2 ev = *(const float2*)(ep + (size_t)row * EE);
      ax += wgt * ev.x;
      ay += wgt * ev.y;
    }
    float2 o = make_float2(ax, ay);
    *(float2*)&ctxp[((size_t)b * 64 + chunk) * EE + e0] = o;
  }
}

// Per b: global softmax over raw scores -> attn; combine ctx partials.
__global__ void finalize_kernel(float* __restrict__ attn,
                                const float* __restrict__ ctxp,
                                const float* __restrict__ mbuf,
                                float* __restrict__ ctx) {
  __shared__ float red[8];
  __shared__ float fc[64];
  int b = blockIdx.x, t = threadIdx.x;
  float* row = attn + (size_t)b * SS;
  float vals[16];
  float m = -3e38f;
#pragma unroll
  for (int i = 0; i < 16; ++i) {
    float x = row[i * 256 + t];
    vals[i] = x;
    m = fmaxf(m, x);
  }
  for (int off = 1; off < 64; off <<= 1) m = fmaxf(m, __shfl_xor(m, off, 64));
  int wv = t >> 6, ln = t & 63;
  if (ln == 0) red[wv] = m;
  __syncthreads();
  m = fmaxf(fmaxf(red[0], red[1]), fmaxf(red[2], red[3]));
  float sum = 0.f;
#pragma unroll
  for (int i = 0; i < 16; ++i) { vals[i] = __expf(vals[i] - m); sum += vals[i]; }
  for (int off = 1; off < 64; off <<= 1) sum += __shfl_xor(sum, off, 64);
  if (ln == 0) red[4 + wv] = sum;
  __syncthreads();
  sum = red[4] + red[5] + red[6] + red[7];
  float inv = 1.f / sum;
#pragma unroll
  for (int i = 0; i < 16; ++i) row[i * 256 + t] = vals[i] * inv;

  if (t < 64) fc[t] = __expf(mbuf[b * 64 + t] - m) * inv;
  __syncthreads();
#pragma unroll
  for (int jj = 0; jj < 2; ++jj) {
    int e = jj * 256 + t;
    const float* p = ctxp + (size_t)b * 64 * EE + e;
    float s = 0.f;
#pragma unroll
    for (int c = 0; c < 64; ++c) s += fc[c] * p[c * EE];
    ctx[b * EE + e] = s;
  }
}

extern "C" void kernel_launch(void* const* d_in, const int* in_sizes, int n_in,
                              void* d_out, int out_size, void* d_ws, size_t ws_size,
                              hipStream_t stream) {
  const float* h    = (const float*)d_in[0];
  const float* enc  = (const float*)d_in[1];
  const int*   mask = (const int*)d_in[2];
  const float* Wh   = (const float*)d_in[3];
  const float* Ws   = (const float*)d_in[4];
  const float* v    = (const float*)d_in[5];

  float* out  = (float*)d_out;
  float* ctx  = out;              // [32,512]
  float* attn = out + BB * EE;    // [32,4096]

  char* ws = (char*)d_ws;
  float* qws = (float*)ws;                    ws += (size_t)BB * AA * 4;        // 64 KB
  unsigned short* Wst = (unsigned short*)ws;  ws += (size_t)AA * EE * 2;        // 512 KB
  float* ctxp = (float*)ws;                   ws += (size_t)BB * 64 * EE * 4;   // 4 MB
  float* mbuf = (float*)ws;                                                     // 8 KB

  hipLaunchKernelGGL(query_kernel, dim3(32), dim3(256), 0, stream, h, Wh, qws);
  hipLaunchKernelGGL(wst_kernel, dim3(1024), dim3(256), 0, stream, Ws, Wst);
  hipLaunchKernelGGL(fused_kernel, dim3(SS / 64, BB), dim3(256), 0, stream,
                     enc, Wst, qws, v, mask, attn, ctxp, mbuf);
  hipLaunchKernelGGL(finalize_kernel, dim3(BB), dim3(256), 0, stream,
                     attn, ctxp, mbuf, ctx);
}

// Round 5
// 604.740 us; speedup vs baseline: 1.2159x; 1.2159x over previous
//
#include <hip/hip_runtime.h>
#include <hip/hip_bf16.h>
#include <math.h>

#define BB 32
#define SS 4096
#define EE 512
#define AA 512

typedef short bf16x8 __attribute__((ext_vector_type(8)));
typedef float f32x4 __attribute__((ext_vector_type(4)));

__device__ __forceinline__ unsigned short f2bf(float f) {
  unsigned int u = __float_as_uint(f);
  u += 0x7fffu + ((u >> 16) & 1u);   // RNE (finite normals)
  return (unsigned short)(u >> 16);
}

__device__ __forceinline__ float tanh_fast(float x) {
  return 1.f - 2.f / (__expf(2.f * x) + 1.f);
}

// pack 8 f32 -> bf16x8 (RNE) via packed cvt
__device__ __forceinline__ bf16x8 pack8(float4 a, float4 b) {
  union { bf16x8 v; __hip_bfloat162 h[4]; } u;
  u.h[0] = __float22bfloat162_rn(make_float2(a.x, a.y));
  u.h[1] = __float22bfloat162_rn(make_float2(a.z, a.w));
  u.h[2] = __float22bfloat162_rn(make_float2(b.x, b.y));
  u.h[3] = __float22bfloat162_rn(make_float2(b.z, b.w));
  return u.v;
}

// q[b][a] = sum_e h[b][e] * Wh[e][a]
__global__ void query_kernel(const float* __restrict__ h,
                             const float* __restrict__ Wh,
                             float* __restrict__ q) {
  __shared__ float hrow[EE];
  int b = blockIdx.x;
  int t = threadIdx.x;
  for (int i = t; i < EE; i += 256) hrow[i] = h[b * EE + i];
  __syncthreads();
  float a0 = 0.f, a1 = 0.f;
  for (int e = 0; e < EE; ++e) {
    float hv = hrow[e];
    a0 += hv * Wh[e * AA + t];
    a1 += hv * Wh[e * AA + t + 256];
  }
  q[b * AA + t] = a0;
  q[b * AA + t + 256] = a1;
}

// Wst[a][e] = bf16(Ws[e][a])
__global__ void wst_kernel(const float* __restrict__ Ws,
                           unsigned short* __restrict__ Wst) {
  int i = blockIdx.x * 256 + threadIdx.x;   // over 512*512
  int a = i >> 9, e = i & 511;
  Wst[a * EE + e] = f2bf(Ws[e * AA + a]);
}

// Fused flash-style: block = (chunk of 32 s-rows, b). 32 KB LDS A-tile ->
// 4 blocks/CU (16 waves). Wave w: M=32 x N=128 (2 passes of 64),
// 8 MFMA : 2 ds_read_b128 : 4 L2-hot B-loads per k-step.
__global__ __launch_bounds__(256, 4) void fused_kernel(
    const float* __restrict__ enc, const unsigned short* __restrict__ Wst,
    const float* __restrict__ q, const float* __restrict__ v,
    const int* __restrict__ mask,
    float* __restrict__ rawscore,   // -> attn region of d_out
    float* __restrict__ ctxp,       // [32][128][512]
    float* __restrict__ mbuf) {     // [32][128]
  // 32 rows x 512 k bf16, XOR-swizzled 16B chunks: chunk' = chunk ^ (row&7)
  __shared__ __align__(16) unsigned short Atile[32 * 512];   // 32 KB
  __shared__ float spart[4][32];
  __shared__ float wrow[32];
  const int b = blockIdx.y, chunk = blockIdx.x;
  const int s0 = chunk * 32;
  const int tid = threadIdx.x;

  // ---- Phase A: stage enc tile f32 -> bf16 (2048 16B-chunks, 8/thread) ----
  const float4* src = (const float4*)(enc + ((size_t)b * SS + s0) * EE);
#pragma unroll 4
  for (int j0 = 0; j0 < 8; ++j0) {
    int j = j0 * 256 + tid;          // 0..2047
    float4 f0 = src[j * 2];
    float4 f1 = src[j * 2 + 1];
    int r = j >> 6, c = j & 63;
    *(bf16x8*)&Atile[r * 512 + ((c ^ (r & 7)) << 3)] = pack8(f0, f1);
  }
  __syncthreads();

  // ---- Phase B: GEMM ----
  const int w = tid >> 6, lane = tid & 63;
  const int quad = lane >> 4, l16 = lane & 15;
  const unsigned short* arow0 = &Atile[l16 * 512];         // rows 0..15
  const unsigned short* arow1 = &Atile[(16 + l16) * 512];  // rows 16..31

  float srow[2][4];
#pragma unroll
  for (int m = 0; m < 2; ++m)
#pragma unroll
    for (int r = 0; r < 4; ++r) srow[m][r] = 0.f;

  for (int h = 0; h < 2; ++h) {
    const int n0 = w * 128 + h * 64;
    f32x4 acc[2][4];
#pragma unroll
    for (int m = 0; m < 2; ++m)
#pragma unroll
      for (int n = 0; n < 4; ++n) acc[m][n] = (f32x4){0.f, 0.f, 0.f, 0.f};

    const unsigned short* wb = Wst + (size_t)(n0 + l16) * EE + quad * 8;
#pragma unroll 2
    for (int k0 = 0; k0 < 512; k0 += 32) {
      int cs = ((k0 >> 3) + quad) ^ (l16 & 7);
      bf16x8 a0 = *(const bf16x8*)&arow0[cs * 8];
      bf16x8 a1 = *(const bf16x8*)&arow1[cs * 8];
      bf16x8 bF[4];
#pragma unroll
      for (int n = 0; n < 4; ++n)
        bF[n] = *(const bf16x8*)&wb[(size_t)n * 16 * EE + k0];
#pragma unroll
      for (int n = 0; n < 4; ++n) {
        acc[0][n] = __builtin_amdgcn_mfma_f32_16x16x32_bf16(a0, bF[n], acc[0][n], 0, 0, 0);
        acc[1][n] = __builtin_amdgcn_mfma_f32_16x16x32_bf16(a1, bF[n], acc[1][n], 0, 0, 0);
      }
    }
    // epilogue: tanh + v-weighted accumulate
#pragma unroll
    for (int n = 0; n < 4; ++n) {
      float qn = q[b * AA + n0 + n * 16 + l16];
      float vn = v[n0 + n * 16 + l16];
#pragma unroll
      for (int m = 0; m < 2; ++m)
#pragma unroll
        for (int r = 0; r < 4; ++r)
          srow[m][r] += tanh_fast(qn + acc[m][n][r]) * vn;
    }
  }

  // reduce across the 16 lanes (n-cols) of each quad
#pragma unroll
  for (int m = 0; m < 2; ++m)
#pragma unroll
    for (int r = 0; r < 4; ++r) {
      float s = srow[m][r];
      s += __shfl_xor(s, 1, 64);
      s += __shfl_xor(s, 2, 64);
      s += __shfl_xor(s, 4, 64);
      s += __shfl_xor(s, 8, 64);
      if (l16 == 0) spart[w][m * 16 + quad * 4 + r] = s;
    }
  __syncthreads();

  // ---- Phase C: masked raw scores, chunk max, exp weights ----
  if (tid < 32) {
    float raw = spart[0][tid] + spart[1][tid] + spart[2][tid] + spart[3][tid];
    float sc = mask[(size_t)b * SS + s0 + tid] ? -1e9f : raw;
    rawscore[(size_t)b * SS + s0 + tid] = sc;
    float mx = sc;
    mx = fmaxf(mx, __shfl_xor(mx, 1, 64));
    mx = fmaxf(mx, __shfl_xor(mx, 2, 64));
    mx = fmaxf(mx, __shfl_xor(mx, 4, 64));
    mx = fmaxf(mx, __shfl_xor(mx, 8, 64));
    mx = fmaxf(mx, __shfl_xor(mx, 16, 64));
    wrow[tid] = __expf(sc - mx);
    if (tid == 0) mbuf[b * 128 + chunk] = mx;
  }
  __syncthreads();

  // ---- Phase D: ctx partial from LDS tile; thread owns 2 e-cols ----
  {
    const int e0 = tid * 2;
    const int c = e0 >> 3;          // 16B chunk of e0
    const int within = e0 & 7;      // even
    float ax = 0.f, ay = 0.f;
#pragma unroll 8
    for (int row = 0; row < 32; ++row) {
      float wgt = wrow[row];
      unsigned int u = *(const unsigned int*)
          &Atile[row * 512 + ((c ^ (row & 7)) << 3) + within];
      float lo = __uint_as_float(u << 16);
      float hi = __uint_as_float(u & 0xffff0000u);
      ax += wgt * lo;
      ay += wgt * hi;
    }
    *(float2*)&ctxp[((size_t)b * 128 + chunk) * EE + e0] = make_float2(ax, ay);
  }
}

// Per b: global softmax over raw scores -> attn; combine ctx partials.
__global__ void finalize_kernel(float* __restrict__ attn,
                                const float* __restrict__ ctxp,
                                const float* __restrict__ mbuf,
                                float* __restrict__ ctx) {
  __shared__ float red[8];
  __shared__ float fc[128];
  int b = blockIdx.x, t = threadIdx.x;
  float* row = attn + (size_t)b * SS;
  float vals[16];
  float m = -3e38f;
#pragma unroll
  for (int i = 0; i < 16; ++i) {
    float x = row[i * 256 + t];
    vals[i] = x;
    m = fmaxf(m, x);
  }
  for (int off = 1; off < 64; off <<= 1) m = fmaxf(m, __shfl_xor(m, off, 64));
  int wv = t >> 6, ln = t & 63;
  if (ln == 0) red[wv] = m;
  __syncthreads();
  m = fmaxf(fmaxf(red[0], red[1]), fmaxf(red[2], red[3]));
  float sum = 0.f;
#pragma unroll
  for (int i = 0; i < 16; ++i) { vals[i] = __expf(vals[i] - m); sum += vals[i]; }
  for (int off = 1; off < 64; off <<= 1) sum += __shfl_xor(sum, off, 64);
  if (ln == 0) red[4 + wv] = sum;
  __syncthreads();
  sum = red[4] + red[5] + red[6] + red[7];
  float inv = 1.f / sum;
#pragma unroll
  for (int i = 0; i < 16; ++i) row[i * 256 + t] = vals[i] * inv;

  if (t < 128) fc[t] = __expf(mbuf[b * 128 + t] - m) * inv;
  __syncthreads();
#pragma unroll
  for (int jj = 0; jj < 2; ++jj) {
    int e = jj * 256 + t;
    const float* p = ctxp + (size_t)b * 128 * EE + e;
    float s = 0.f;
    for (int c = 0; c < 128; ++c) s += fc[c] * p[c * EE];
    ctx[b * EE + e] = s;
  }
}

extern "C" void kernel_launch(void* const* d_in, const int* in_sizes, int n_in,
                              void* d_out, int out_size, void* d_ws, size_t ws_size,
                              hipStream_t stream) {
  const float* h    = (const float*)d_in[0];
  const float* enc  = (const float*)d_in[1];
  const int*   mask = (const int*)d_in[2];
  const float* Wh   = (const float*)d_in[3];
  const float* Ws   = (const float*)d_in[4];
  const float* v    = (const float*)d_in[5];

  float* out  = (float*)d_out;
  float* ctx  = out;              // [32,512]
  float* attn = out + BB * EE;    // [32,4096]

  char* ws = (char*)d_ws;
  float* qws = (float*)ws;                    ws += (size_t)BB * AA * 4;         // 64 KB
  unsigned short* Wst = (unsigned short*)ws;  ws += (size_t)AA * EE * 2;         // 512 KB
  float* ctxp = (float*)ws;                   ws += (size_t)BB * 128 * EE * 4;   // 8 MB
  float* mbuf = (float*)ws;                                                      // 16 KB

  hipLaunchKernelGGL(query_kernel, dim3(32), dim3(256), 0, stream, h, Wh, qws);
  hipLaunchKernelGGL(wst_kernel, dim3(1024), dim3(256), 0, stream, Ws, Wst);
  hipLaunchKernelGGL(fused_kernel, dim3(SS / 32, BB), dim3(256), 0, stream,
                     enc, Wst, qws, v, mask, attn, ctxp, mbuf);
  hipLaunchKernelGGL(finalize_kernel, dim3(BB), dim3(256), 0, stream,
                     attn, ctxp, mbuf, ctx);
}